// Round 10
// baseline (364.986 us; speedup 1.0000x reference)
//
#include <hip/hip_runtime.h>
#include <hip/hip_bf16.h>
#include <math.h>

#define EMBED 768
#define HEADS 12
#define HEAD_DIM 64
#define HIDDEN 3072
#define SEQ 1024
#define BATCH 8
#define TOKENS (SEQ*BATCH)

typedef unsigned short u16;
typedef __attribute__((ext_vector_type(8))) short bf16x8;
typedef __attribute__((ext_vector_type(4))) float floatx4;
typedef __attribute__((ext_vector_type(4))) u16 u16x4;
typedef __attribute__((ext_vector_type(2))) u16 u16x2;

__device__ __forceinline__ u16 f2bf(float f){
    union { float f; unsigned u; } v; v.f = f;
    unsigned r = v.u + 0x7fffu + ((v.u >> 16) & 1u);
    return (u16)(r >> 16);
}

// packed f32x2 -> bf16x2 (RNE, same as f2bf) in one VALU op
__device__ __forceinline__ unsigned cvt_pk_bf16(float lo, float hi){
    unsigned r;
    asm("v_cvt_pk_bf16_f32 %0, %1, %2" : "=v"(r) : "v"(lo), "v"(hi));
    return r;
}

__device__ __forceinline__ void gload16(const void* g, void* l){
    __builtin_amdgcn_global_load_lds((const __attribute__((address_space(1))) void*)g,
                                     (__attribute__((address_space(3))) void*)l, 16, 0, 0);
}

// fast GELU (tanh approx, sigmoid form): abs err ~1e-3, fine vs 0.109 threshold
__device__ __forceinline__ float gelu_fast(float x){
    float t = 1.5957691216f * (x + 0.044715f * x * x * x);
    return x / (1.0f + __expf(-t));
}

// ---------------- prep: 4x weight cast+transpose + LN1, one launch ----------------
__global__ __launch_bounds__(256) void prep_kernel(const float* __restrict__ w0, const float* __restrict__ w1,
                                   const float* __restrict__ w2, const float* __restrict__ w3,
                                   u16* __restrict__ o0, u16* __restrict__ o1,
                                   u16* __restrict__ o2, u16* __restrict__ o3,
                                   const float* __restrict__ x, const float* __restrict__ g,
                                   const float* __restrict__ bln, u16* __restrict__ lnout){
    int bb = blockIdx.x;
    int tid = threadIdx.x;
    if(bb >= 6912){
        int row  = (bb - 6912) * 4 + (tid >> 6);
        int lane = tid & 63;
        const float4* xr = (const float4*)(x + (size_t)row * EMBED);
        float4 v[3];
        float s = 0.f;
        #pragma unroll
        for(int i=0;i<3;i++){
            v[i] = xr[i*64 + lane];
            s += v[i].x + v[i].y + v[i].z + v[i].w;
        }
        #pragma unroll
        for(int o=32;o>0;o>>=1) s += __shfl_xor(s, o);
        float mu = s * (1.0f/EMBED);
        float s2 = 0.f;
        #pragma unroll
        for(int i=0;i<3;i++){
            float dx = v[i].x-mu, dy = v[i].y-mu, dz = v[i].z-mu, dw = v[i].w-mu;
            s2 += dx*dx + dy*dy + dz*dz + dw*dw;
        }
        #pragma unroll
        for(int o=32;o>0;o>>=1) s2 += __shfl_xor(s2, o);
        float rstd = rsqrtf(s2*(1.0f/EMBED) + 1e-5f);
        u16* orow = lnout + (size_t)row * EMBED;
        const float4* g4 = (const float4*)g;
        const float4* b4 = (const float4*)bln;
        #pragma unroll
        for(int i=0;i<3;i++){
            int c4 = i*64 + lane;
            float4 gv = g4[c4], bv = b4[c4];
            u16x4 pk;
            pk.x = f2bf((v[i].x-mu)*rstd*gv.x + bv.x);
            pk.y = f2bf((v[i].y-mu)*rstd*gv.y + bv.y);
            pk.z = f2bf((v[i].z-mu)*rstd*gv.z + bv.z);
            pk.w = f2bf((v[i].w-mu)*rstd*gv.w + bv.w);
            *(u16x4*)(orow + c4*4) = pk;
        }
        return;
    }
    const float* W; u16* Wt; int K, N, bx, by;
    if(bb < 1728)      { int l = bb;        W=w0; Wt=o0; K=768;  N=2304; bx=l%72; by=l/72; }
    else if(bb < 2304) { int l = bb-1728;   W=w1; Wt=o1; K=768;  N=768;  bx=l%24; by=l/24; }
    else if(bb < 4608) { int l = bb-2304;   W=w2; Wt=o2; K=768;  N=3072; bx=l%96; by=l/96; }
    else               { int l = bb-4608;   W=w3; Wt=o3; K=3072; N=768;  bx=l%24; by=l/24; }

    __shared__ float tile[32][33];
    int n0 = bx * 32, k0 = by * 32;
    int tx = tid & 31, ty = tid >> 5;
    #pragma unroll
    for(int i=0;i<32;i+=8) tile[ty+i][tx] = W[(size_t)(k0+ty+i)*N + n0+tx];
    __syncthreads();
    int kp = (tid & 15)*2, nn = tid >> 4;
    #pragma unroll
    for(int p=0;p<2;p++){
        int n = nn + p*16;
        u16x2 w2v;
        w2v.x = f2bf(tile[kp  ][n]);
        w2v.y = f2bf(tile[kp+1][n]);
        *(u16x2*)(Wt + (size_t)(n0+n)*K + k0 + kp) = w2v;
    }
}

// ---------------- layernorm standalone (LN2) ----------------
__global__ __launch_bounds__(256) void ln_kernel(const float* __restrict__ x, const float* __restrict__ g,
                                                 const float* __restrict__ b, u16* __restrict__ out){
    int row  = blockIdx.x * 4 + (threadIdx.x >> 6);
    int lane = threadIdx.x & 63;
    const float4* xr = (const float4*)(x + (size_t)row * EMBED);
    float4 v[3];
    float s = 0.f;
    #pragma unroll
    for(int i=0;i<3;i++){
        v[i] = xr[i*64 + lane];
        s += v[i].x + v[i].y + v[i].z + v[i].w;
    }
    #pragma unroll
    for(int o=32;o>0;o>>=1) s += __shfl_xor(s, o);
    float mu = s * (1.0f/EMBED);
    float s2 = 0.f;
    #pragma unroll
    for(int i=0;i<3;i++){
        float dx = v[i].x-mu, dy = v[i].y-mu, dz = v[i].z-mu, dw = v[i].w-mu;
        s2 += dx*dx + dy*dy + dz*dz + dw*dw;
    }
    #pragma unroll
    for(int o=32;o>0;o>>=1) s2 += __shfl_xor(s2, o);
    float rstd = rsqrtf(s2*(1.0f/EMBED) + 1e-5f);
    u16* orow = out + (size_t)row * EMBED;
    const float4* g4 = (const float4*)g;
    const float4* b4 = (const float4*)b;
    #pragma unroll
    for(int i=0;i<3;i++){
        int c4 = i*64 + lane;
        float4 gv = g4[c4], bv = b4[c4];
        u16x4 pk;
        pk.x = f2bf((v[i].x-mu)*rstd*gv.x + bv.x);
        pk.y = f2bf((v[i].y-mu)*rstd*gv.y + bv.y);
        pk.z = f2bf((v[i].z-mu)*rstd*gv.z + bv.z);
        pk.w = f2bf((v[i].w-mu)*rstd*gv.w + bv.w);
        *(u16x4*)(orow + c4*4) = pk;
    }
}

// ---------------- GEMM wide: 128x256, BK=32, FULL double-buffer, counted vmcnt(3) -------
// LDS 48KB -> 3 blocks/CU. Per iter: issue tile t+1's 3 loads; vmcnt(3) retires tile t
// (issued a full compute + 2 barriers earlier -> latency fully covered for BOTH operands).
// BK=32 swizzle (bank-correct): swz(r)=(r>>1)&3; lds[r][c]=g[r][c^swz(r)], read chunk
// quad^((lm>>1)&3). Aligned 8-lane groups then cover all 8 bank-quads:
// bankq(lane) = 16*(lm&1)+4*(quad^((lm>>1)&3)) -> {0,16,4,20,8,24,12,28} for lanes 0..7.
// (Round-9's (r>>2) variant paired lanes on one bank-quad -> 7M conflicts. Fixed.)
template<int EPI>
__global__ __launch_bounds__(512,2) void gemm_wide(const u16* __restrict__ A, const u16* __restrict__ Bt,
        void* __restrict__ Cout, const float* __restrict__ bias, const float* __restrict__ res,
        u16* __restrict__ vt, int M, int N, int K, int ldc){
    constexpr int ASZ = 128*32;                  // u16 per A buffer (8 KB)
    constexpr int BSZ = 256*32;                  // u16 per B buffer (16 KB)
    __shared__ __align__(16) u16 As[2*ASZ];
    __shared__ __align__(16) u16 Bs[2*BSZ];
    int tid  = threadIdx.x;
    int wave = tid >> 6, lane = tid & 63;
    int quad = lane >> 4, lm = lane & 15;
    int wm = (wave >> 2) * 64;
    int wn = (wave & 3) * 64;

    int gx = gridDim.x;
    int bid = blockIdx.y * gx + blockIdx.x;
    int nwg = gx * gridDim.y;
    int cpx = nwg >> 3;
    int swz = (bid & 7) * cpx + (bid >> 3);
    int m0 = (swz / gx) * 128, n0 = (swz % gx) * 256;

    floatx4 acc[4][4];
    #pragma unroll
    for(int i=0;i<4;i++)
        #pragma unroll
        for(int j=0;j<4;j++) acc[i][j] = (floatx4){0.f,0.f,0.f,0.f};

    int srow = tid >> 2;                              // 0..127
    int scol = ((tid & 3) ^ ((tid >> 3) & 3)) * 8;    // swz(row)=(row>>1)&3, row=tid>>2
    const u16* aP  = A  + (size_t)(m0 + srow) * K + scol;
    const u16* bP0 = Bt + (size_t)(n0 + srow) * K + scol;
    const u16* bP1 = Bt + (size_t)(n0 + 128 + srow) * K + scol;
    int cr8 = (quad ^ ((lm >> 1) & 3)) * 8;           // read chunk offset (u16)

    int nt = K / 32;

    // prologue: tile 0 into buf 0
    gload16(aP,  As + tid*8);
    gload16(bP0, Bs + tid*8);
    gload16(bP1, Bs + 4096 + tid*8);

    for(int t=0; t<nt; ++t){
        int cur = t & 1, nxt = cur ^ 1;
        if(t+1 < nt){
            size_t ko = (size_t)(t+1) * 32;
            gload16(aP  + ko, As + nxt*ASZ + tid*8);
            gload16(bP0 + ko, Bs + nxt*BSZ + tid*8);
            gload16(bP1 + ko, Bs + nxt*BSZ + 4096 + tid*8);
            asm volatile("s_waitcnt vmcnt(3)" ::: "memory");  // retire tile t (full-iter cover)
        } else {
            asm volatile("s_waitcnt vmcnt(0)" ::: "memory");
        }
        __builtin_amdgcn_s_barrier();
        const u16* Ac = As + cur*ASZ;
        const u16* Bc = Bs + cur*BSZ;
        bf16x8 af[4], bfr[4];
        #pragma unroll
        for(int mf=0;mf<4;mf++)
            af[mf]  = *(const bf16x8*)(Ac + (wm + mf*16 + lm)*32 + cr8);
        #pragma unroll
        for(int nf=0;nf<4;nf++)
            bfr[nf] = *(const bf16x8*)(Bc + (wn + nf*16 + lm)*32 + cr8);
        #pragma unroll
        for(int mf=0;mf<4;mf++)
            #pragma unroll
            for(int nf=0;nf<4;nf++)
                acc[mf][nf] = __builtin_amdgcn_mfma_f32_16x16x32_bf16(af[mf], bfr[nf], acc[mf][nf], 0, 0, 0);
        __builtin_amdgcn_s_barrier();
    }

    if(EPI == 3 && n0 >= 1536){
        #pragma unroll
        for(int nf=0;nf<4;nf++){
            int col = n0 + wn + nf*16 + lm;
            int hh = (col - 1536) >> 6;
            int d  = col & 63;
            #pragma unroll
            for(int mf=0;mf<4;mf++){
                int row0 = m0 + wm + mf*16 + quad*4;
                int bb  = row0 >> 10;
                int key = row0 & 1023;
                u16x4 pk;
                #pragma unroll
                for(int r=0;r<4;r++) pk[r] = f2bf(acc[mf][nf][r]);
                *(u16x4*)(vt + ((size_t)(bb*HEADS+hh)*64 + d)*SEQ + key) = pk;
            }
        }
        return;
    }

    float bvv[4];
    #pragma unroll
    for(int nf=0;nf<4;nf++) bvv[nf] = bias ? bias[n0 + wn + nf*16 + lm] : 0.f;
    #pragma unroll
    for(int mf=0;mf<4;mf++){
        int row0 = m0 + wm + mf*16 + quad*4;
        #pragma unroll
        for(int r=0;r<4;r++){
            size_t rowoff = (size_t)(row0 + r) * ldc;
            #pragma unroll
            for(int nf=0;nf<4;nf++){              // nf innermost: row's line fills contiguously
                int col = n0 + wn + nf*16 + lm;
                float v = acc[mf][nf][r] + bvv[nf];
                if(EPI == 1) v = gelu_fast(v);
                if(EPI == 3 && col < 768) v *= 0.18033688011112186f;  // Q prescale: 0.125*log2(e)
                ((u16*)Cout)[rowoff + col] = f2bf(v);
            }
        }
    }
}

// ---------------- GEMM narrow: 64x128, BK=32, FULL double-buffer, counted vmcnt(3) ------
// LDS 24KB -> 6 blocks/CU. Same (fixed) swizzle/ledger as gemm_wide.
// EPI 2: bias + fp32 residual -> fp32 (proj, fc2).
template<int EPI>
__global__ __launch_bounds__(256,4) void gemm_nar(const u16* __restrict__ A, const u16* __restrict__ Bt,
        void* __restrict__ Cout, const float* __restrict__ bias, const float* __restrict__ res,
        u16* __restrict__ vt, int M, int N, int K, int ldc){
    constexpr int ASZ = 64*32;                   // 4 KB
    constexpr int BSZ = 128*32;                  // 8 KB
    __shared__ __align__(16) u16 As[2*ASZ];
    __shared__ __align__(16) u16 Bs[2*BSZ];
    int tid  = threadIdx.x;
    int wave = tid >> 6, lane = tid & 63;
    int quad = lane >> 4, lm = lane & 15;

    int gx = gridDim.x;
    int bid = blockIdx.y * gx + blockIdx.x;
    int nwg = gx * gridDim.y;
    int cpx = nwg >> 3;
    int swz = (bid & 7) * cpx + (bid >> 3);
    int m0 = (swz / gx) * 64, n0 = (swz % gx) * 128;

    int wm = (wave & 1) * 32;
    int wn = (wave >> 1) * 64;

    floatx4 acc[2][4];
    #pragma unroll
    for(int i=0;i<2;i++)
        #pragma unroll
        for(int j=0;j<4;j++) acc[i][j] = (floatx4){0.f,0.f,0.f,0.f};

    int srow = tid >> 2;                              // 0..63
    int scol = ((tid & 3) ^ ((tid >> 3) & 3)) * 8;    // swz(row)=(row>>1)&3
    const u16* aP  = A  + (size_t)(m0 + srow) * K + scol;
    const u16* bP0 = Bt + (size_t)(n0 + srow) * K + scol;
    const u16* bP1 = Bt + (size_t)(n0 + 64 + srow) * K + scol;
    int cr8 = (quad ^ ((lm >> 1) & 3)) * 8;

    int nt = K / 32;

    gload16(aP,  As + tid*8);
    gload16(bP0, Bs + tid*8);
    gload16(bP1, Bs + 2048 + tid*8);

    for(int t=0; t<nt; ++t){
        int cur = t & 1, nxt = cur ^ 1;
        if(t+1 < nt){
            size_t ko = (size_t)(t+1) * 32;
            gload16(aP  + ko, As + nxt*ASZ + tid*8);
            gload16(bP0 + ko, Bs + nxt*BSZ + tid*8);
            gload16(bP1 + ko, Bs + nxt*BSZ + 2048 + tid*8);
            asm volatile("s_waitcnt vmcnt(3)" ::: "memory");
        } else {
            asm volatile("s_waitcnt vmcnt(0)" ::: "memory");
        }
        __builtin_amdgcn_s_barrier();
        const u16* Ac = As + cur*ASZ;
        const u16* Bc = Bs + cur*BSZ;
        bf16x8 af[2], bfr[4];
        #pragma unroll
        for(int mf=0;mf<2;mf++)
            af[mf]  = *(const bf16x8*)(Ac + (wm + mf*16 + lm)*32 + cr8);
        #pragma unroll
        for(int nf=0;nf<4;nf++)
            bfr[nf] = *(const bf16x8*)(Bc + (wn + nf*16 + lm)*32 + cr8);
        #pragma unroll
        for(int mf=0;mf<2;mf++)
            #pragma unroll
            for(int nf=0;nf<4;nf++)
                acc[mf][nf] = __builtin_amdgcn_mfma_f32_16x16x32_bf16(af[mf], bfr[nf], acc[mf][nf], 0, 0, 0);
        __builtin_amdgcn_s_barrier();
    }

    float bvv[4];
    #pragma unroll
    for(int nf=0;nf<4;nf++) bvv[nf] = bias ? bias[n0 + wn + nf*16 + lm] : 0.f;
    #pragma unroll
    for(int mf=0;mf<2;mf++){
        int row0 = m0 + wm + mf*16 + quad*4;
        #pragma unroll
        for(int r=0;r<4;r++){
            size_t rowoff = (size_t)(row0 + r) * ldc;
            #pragma unroll
            for(int nf=0;nf<4;nf++){
                int col = n0 + wn + nf*16 + lm;
                float v = acc[mf][nf][r] + bvv[nf];
                if(EPI == 2){
                    ((float*)Cout)[rowoff + col] = v + res[rowoff + col];
                } else {
                    ((u16*)Cout)[rowoff + col] = f2bf(v);
                }
            }
        }
    }
}

// ---------------- flash attention: S^T formulation, VALU-lean softmax ----------------
__global__ __launch_bounds__(256) void attn_kernel(const u16* __restrict__ qk, const u16* __restrict__ vt,
                                                   u16* __restrict__ out){
    int bid = blockIdx.x;
    int hb = bid % 96;
    int qt = bid / 96;
    int h = hb % HEADS, b = hb / HEADS;
    int tid = threadIdx.x;
    int wave = tid >> 6, lane = tid & 63;
    int quad = lane >> 4, lm = lane & 15;

    __shared__ __align__(16) u16 Ks[2*64*64];
    __shared__ __align__(16) u16 Vs[2*64*64];
    __shared__ __align__(16) u16 P[4*32*64];

    const u16* qbase = qk + (size_t)b * SEQ * 1536;
    const u16* vbase = vt + (size_t)(b*HEADS + h) * 64 * SEQ;
    u16* Pw = P + wave*2048;

    int q0 = qt*128 + wave*32;
    bf16x8 qf[2][2];
    #pragma unroll
    for(int qi=0;qi<2;qi++){
        const u16* qp = qbase + (size_t)(q0 + qi*16 + lm)*1536 + h*64;
        qf[qi][0] = *(const bf16x8*)(qp + quad*8);
        qf[qi][1] = *(const bf16x8*)(qp + 32 + quad*8);
    }

    float l_i[2] = {0.f, 0.f};
    floatx4 o_acc[2][4];
    #pragma unroll
    for(int qi=0;qi<2;qi++)
        #pragma unroll
        for(int nf=0;nf<4;nf++) o_acc[qi][nf] = (floatx4){0.f,0.f,0.f,0.f};

    int sr = lane >> 3;
    int sp = lane & 7;

    auto stage = [&](int kt, int buf){
        #pragma unroll
        for(int i=0;i<2;i++){
            int rr = wave*16 + i*8 + sr;
            int sw = (sp ^ (rr & 7)) * 8;
            gload16(qbase + (size_t)(kt*64 + rr)*1536 + 768 + h*64 + sw,
                    Ks + buf*4096 + (wave*16 + i*8)*64 + lane*8);
            gload16(vbase + (size_t)rr*SEQ + kt*64 + sw,
                    Vs + buf*4096 + (wave*16 + i*8)*64 + lane*8);
        }
    };

    stage(0, 0);
    __syncthreads();

    int cur = 0;
    for(int kt=0; kt<16; kt++){
        if(kt < 15) stage(kt+1, cur^1);
        const u16* Ksb = Ks + cur*4096;
        const u16* Vsb = Vs + cur*4096;

        floatx4 s[4][2];
        #pragma unroll
        for(int kf=0;kf<4;kf++){
            int krow = kf*16 + lm;
            bf16x8 k0 = *(const bf16x8*)(Ksb + krow*64 + ((quad     ^ (lm&7))*8));
            bf16x8 k1 = *(const bf16x8*)(Ksb + krow*64 + (((4+quad) ^ (lm&7))*8));
            #pragma unroll
            for(int qi=0;qi<2;qi++){
                floatx4 t = (floatx4){0.f,0.f,0.f,0.f};
                t = __builtin_amdgcn_mfma_f32_16x16x32_bf16(k0, qf[qi][0], t, 0, 0, 0);
                t = __builtin_amdgcn_mfma_f32_16x16x32_bf16(k1, qf[qi][1], t, 0, 0, 0);
                s[kf][qi] = t;
            }
        }

        #pragma unroll
        for(int qi=0;qi<2;qi++){
            float part = 0.f;
            #pragma unroll
            for(int kf=0;kf<4;kf++){
                #pragma unroll
                for(int r=0;r<4;r++){
                    float e = exp2f(s[kf][qi][r]);     // Q prescaled: no *C
                    s[kf][qi][r] = e;
                    part += e;
                }
            }
            l_i[qi] += part;
            #pragma unroll
            for(int kf=0;kf<4;kf++){
                uint2 pk2;
                pk2.x = cvt_pk_bf16(s[kf][qi][0], s[kf][qi][1]);
                pk2.y = cvt_pk_bf16(s[kf][qi][2], s[kf][qi][3]);
                int c  = kf*4 + quad;
                int cp = c ^ (2*(lm & 7));
                *(uint2*)(Pw + (qi*16 + lm)*64 + cp*4) = pk2;
            }
        }

        #pragma unroll
        for(int ks=0;ks<2;ks++){
            bf16x8 vf[4];
            #pragma unroll
            for(int nf=0;nf<4;nf++)
                vf[nf] = *(const bf16x8*)(Vsb + (nf*16+lm)*64 + (((ks*4+quad) ^ (lm&7))*8));
            #pragma unroll
            for(int qi=0;qi<2;qi++){
                int cr = (ks*8 + 2*quad) ^ (2*(lm & 7));
                bf16x8 pa = *(const bf16x8*)(Pw + (qi*16 + lm)*64 + cr*4);
                #pragma unroll
                for(int nf=0;nf<4;nf++)
                    o_acc[qi][nf] = __builtin_amdgcn_mfma_f32_16x16x32_bf16(pa, vf[nf], o_acc[qi][nf], 0, 0, 0);
            }
        }
        if(kt < 15) __syncthreads();
        cur ^= 1;
    }

    #pragma unroll
    for(int qi=0;qi<2;qi++){
        float lf = l_i[qi];
        lf += __shfl_xor(lf, 16);
        lf += __shfl_xor(lf, 32);
        float rl[4];
        #pragma unroll
        for(int r=0;r<4;r++) rl[r] = 1.0f / __shfl(lf, quad*4 + r);
        int token = b*SEQ + qt*128 + wave*32 + qi*16 + quad*4;
        #pragma unroll
        for(int r=0;r<4;r++){
            size_t rowoff = (size_t)(token + r)*EMBED + h*64;
            #pragma unroll
            for(int nf=0;nf<4;nf++){
                out[rowoff + nf*16 + lm] = f2bf(o_acc[qi][nf][r] * rl[r]);
            }
        }
    }
}

extern "C" void kernel_launch(void* const* d_in, const int* in_sizes, int n_in,
                              void* d_out, int out_size, void* d_ws, size_t ws_size,
                              hipStream_t stream) {
    const float* x      = (const float*)d_in[0];
    const float* g1     = (const float*)d_in[1];
    const float* b1     = (const float*)d_in[2];
    const float* g2     = (const float*)d_in[3];
    const float* b2     = (const float*)d_in[4];
    const float* w_qkv  = (const float*)d_in[5];
    const float* w_proj = (const float*)d_in[6];
    const float* b_proj = (const float*)d_in[7];
    const float* w_fc1  = (const float*)d_in[8];
    const float* b_fc1  = (const float*)d_in[9];
    const float* w_fc2  = (const float*)d_in[10];
    const float* b_fc2  = (const float*)d_in[11];
    float* out = (float*)d_out;

    char* ws = (char*)d_ws;
    u16*   wqkv_t  = (u16*)  (ws + 0);
    u16*   wproj_t = (u16*)  (ws + 3538944);
    u16*   wfc1_t  = (u16*)  (ws + 4718592);
    u16*   wfc2_t  = (u16*)  (ws + 9437184);
    float* x1      = (float*)(ws + 14155776);
    u16*   hbuf    = (u16*)  (ws + 39321600);
    u16*   qkbuf   = (u16*)  (ws + 51904512);
    u16*   vtbuf   = (u16*)  (ws + 77070336);
    u16*   attn_o  = (u16*)  (ws + 89653248);
    u16*   fc1_o   = qkbuf;
    u16*   h2      = hbuf;

    prep_kernel<<<8960, 256, 0, stream>>>(w_qkv, w_proj, w_fc1, w_fc2,
                                          wqkv_t, wproj_t, wfc1_t, wfc2_t,
                                          x, g1, b1, hbuf);

    gemm_wide<3><<<dim3(2304/256, TOKENS/128), 512, 0, stream>>>(hbuf, wqkv_t, qkbuf, nullptr, nullptr, vtbuf, TOKENS, 2304, 768, 1536);

    attn_kernel<<<768, 256, 0, stream>>>(qkbuf, vtbuf, attn_o);

    gemm_nar<2><<<dim3( 768/128, TOKENS/64), 256, 0, stream>>>(attn_o, wproj_t, x1, b_proj, x, nullptr, TOKENS, 768, 768, 768);

    ln_kernel<<<TOKENS/4, 256, 0, stream>>>(x1, g2, b2, h2);

    gemm_wide<1><<<dim3(3072/256, TOKENS/128), 512, 0, stream>>>(h2, wfc1_t, fc1_o, b_fc1, nullptr, nullptr, TOKENS, 3072, 768, 3072);

    gemm_nar<2><<<dim3( 768/128, TOKENS/64), 256, 0, stream>>>(fc1_o, wfc2_t, out, b_fc2, x1, nullptr, TOKENS, 768, 3072, 768);
}

// Round 11
// 331.609 us; speedup vs baseline: 1.1007x; 1.1007x over previous
//
#include <hip/hip_runtime.h>
#include <hip/hip_bf16.h>
#include <math.h>

#define EMBED 768
#define HEADS 12
#define HEAD_DIM 64
#define HIDDEN 3072
#define SEQ 1024
#define BATCH 8
#define TOKENS (SEQ*BATCH)

typedef unsigned short u16;
typedef __attribute__((ext_vector_type(8))) short bf16x8;
typedef __attribute__((ext_vector_type(4))) float floatx4;
typedef __attribute__((ext_vector_type(4))) u16 u16x4;
typedef __attribute__((ext_vector_type(2))) u16 u16x2;

__device__ __forceinline__ u16 f2bf(float f){
    union { float f; unsigned u; } v; v.f = f;
    unsigned r = v.u + 0x7fffu + ((v.u >> 16) & 1u);
    return (u16)(r >> 16);
}

// packed f32x2 -> bf16x2 (RNE, same as f2bf) in one VALU op
__device__ __forceinline__ unsigned cvt_pk_bf16(float lo, float hi){
    unsigned r;
    asm("v_cvt_pk_bf16_f32 %0, %1, %2" : "=v"(r) : "v"(lo), "v"(hi));
    return r;
}

__device__ __forceinline__ void gload16(const void* g, void* l){
    __builtin_amdgcn_global_load_lds((const __attribute__((address_space(1))) void*)g,
                                     (__attribute__((address_space(3))) void*)l, 16, 0, 0);
}

// fast GELU (tanh approx, sigmoid form): abs err ~1e-3, fine vs 0.109 threshold
__device__ __forceinline__ float gelu_fast(float x){
    float t = 1.5957691216f * (x + 0.044715f * x * x * x);
    return x / (1.0f + __expf(-t));
}

// ---------------- prep: 4x weight cast+transpose + LN1, one launch ----------------
__global__ __launch_bounds__(256) void prep_kernel(const float* __restrict__ w0, const float* __restrict__ w1,
                                   const float* __restrict__ w2, const float* __restrict__ w3,
                                   u16* __restrict__ o0, u16* __restrict__ o1,
                                   u16* __restrict__ o2, u16* __restrict__ o3,
                                   const float* __restrict__ x, const float* __restrict__ g,
                                   const float* __restrict__ bln, u16* __restrict__ lnout){
    int bb = blockIdx.x;
    int tid = threadIdx.x;
    if(bb >= 6912){
        int row  = (bb - 6912) * 4 + (tid >> 6);
        int lane = tid & 63;
        const float4* xr = (const float4*)(x + (size_t)row * EMBED);
        float4 v[3];
        float s = 0.f;
        #pragma unroll
        for(int i=0;i<3;i++){
            v[i] = xr[i*64 + lane];
            s += v[i].x + v[i].y + v[i].z + v[i].w;
        }
        #pragma unroll
        for(int o=32;o>0;o>>=1) s += __shfl_xor(s, o);
        float mu = s * (1.0f/EMBED);
        float s2 = 0.f;
        #pragma unroll
        for(int i=0;i<3;i++){
            float dx = v[i].x-mu, dy = v[i].y-mu, dz = v[i].z-mu, dw = v[i].w-mu;
            s2 += dx*dx + dy*dy + dz*dz + dw*dw;
        }
        #pragma unroll
        for(int o=32;o>0;o>>=1) s2 += __shfl_xor(s2, o);
        float rstd = rsqrtf(s2*(1.0f/EMBED) + 1e-5f);
        u16* orow = lnout + (size_t)row * EMBED;
        const float4* g4 = (const float4*)g;
        const float4* b4 = (const float4*)bln;
        #pragma unroll
        for(int i=0;i<3;i++){
            int c4 = i*64 + lane;
            float4 gv = g4[c4], bv = b4[c4];
            u16x4 pk;
            pk.x = f2bf((v[i].x-mu)*rstd*gv.x + bv.x);
            pk.y = f2bf((v[i].y-mu)*rstd*gv.y + bv.y);
            pk.z = f2bf((v[i].z-mu)*rstd*gv.z + bv.z);
            pk.w = f2bf((v[i].w-mu)*rstd*gv.w + bv.w);
            *(u16x4*)(orow + c4*4) = pk;
        }
        return;
    }
    const float* W; u16* Wt; int K, N, bx, by;
    if(bb < 1728)      { int l = bb;        W=w0; Wt=o0; K=768;  N=2304; bx=l%72; by=l/72; }
    else if(bb < 2304) { int l = bb-1728;   W=w1; Wt=o1; K=768;  N=768;  bx=l%24; by=l/24; }
    else if(bb < 4608) { int l = bb-2304;   W=w2; Wt=o2; K=768;  N=3072; bx=l%96; by=l/96; }
    else               { int l = bb-4608;   W=w3; Wt=o3; K=3072; N=768;  bx=l%24; by=l/24; }

    __shared__ float tile[32][33];
    int n0 = bx * 32, k0 = by * 32;
    int tx = tid & 31, ty = tid >> 5;
    #pragma unroll
    for(int i=0;i<32;i+=8) tile[ty+i][tx] = W[(size_t)(k0+ty+i)*N + n0+tx];
    __syncthreads();
    int kp = (tid & 15)*2, nn = tid >> 4;
    #pragma unroll
    for(int p=0;p<2;p++){
        int n = nn + p*16;
        u16x2 w2v;
        w2v.x = f2bf(tile[kp  ][n]);
        w2v.y = f2bf(tile[kp+1][n]);
        *(u16x2*)(Wt + (size_t)(n0+n)*K + k0 + kp) = w2v;
    }
}

// ---------------- layernorm standalone (LN2) ----------------
__global__ __launch_bounds__(256) void ln_kernel(const float* __restrict__ x, const float* __restrict__ g,
                                                 const float* __restrict__ b, u16* __restrict__ out){
    int row  = blockIdx.x * 4 + (threadIdx.x >> 6);
    int lane = threadIdx.x & 63;
    const float4* xr = (const float4*)(x + (size_t)row * EMBED);
    float4 v[3];
    float s = 0.f;
    #pragma unroll
    for(int i=0;i<3;i++){
        v[i] = xr[i*64 + lane];
        s += v[i].x + v[i].y + v[i].z + v[i].w;
    }
    #pragma unroll
    for(int o=32;o>0;o>>=1) s += __shfl_xor(s, o);
    float mu = s * (1.0f/EMBED);
    float s2 = 0.f;
    #pragma unroll
    for(int i=0;i<3;i++){
        float dx = v[i].x-mu, dy = v[i].y-mu, dz = v[i].z-mu, dw = v[i].w-mu;
        s2 += dx*dx + dy*dy + dz*dz + dw*dw;
    }
    #pragma unroll
    for(int o=32;o>0;o>>=1) s2 += __shfl_xor(s2, o);
    float rstd = rsqrtf(s2*(1.0f/EMBED) + 1e-5f);
    u16* orow = out + (size_t)row * EMBED;
    const float4* g4 = (const float4*)g;
    const float4* b4 = (const float4*)b;
    #pragma unroll
    for(int i=0;i<3;i++){
        int c4 = i*64 + lane;
        float4 gv = g4[c4], bv = b4[c4];
        u16x4 pk;
        pk.x = f2bf((v[i].x-mu)*rstd*gv.x + bv.x);
        pk.y = f2bf((v[i].y-mu)*rstd*gv.y + bv.y);
        pk.z = f2bf((v[i].z-mu)*rstd*gv.z + bv.z);
        pk.w = f2bf((v[i].w-mu)*rstd*gv.w + bv.w);
        *(u16x4*)(orow + c4*4) = pk;
    }
}

// ---------------- GEMM wide: 128x256, BK=64, B-double-buffer + counted vmcnt(4) ---------
// (round-8 proven: 58 us, 0 conflicts). A staged same-iter (L2-hot via T1 chunking);
// B(t+1) issued during t -> full-iter cover. LDS 80KB -> 2 blocks/CU.
// EPI 1: bias+GELU->bf16. EPI 3: qkv (Q prescale 0.125*log2e; V transposed to vt).
template<int EPI>
__global__ __launch_bounds__(512,4) void gemm_wide(const u16* __restrict__ A, const u16* __restrict__ Bt,
        void* __restrict__ Cout, const float* __restrict__ bias, const float* __restrict__ res,
        u16* __restrict__ vt, int M, int N, int K, int ldc){
    __shared__ __align__(16) u16 As[128*64];     // 16 KB
    __shared__ __align__(16) u16 Bs[2*256*64];   // 64 KB (double-buffered)
    int tid  = threadIdx.x;
    int wave = tid >> 6, lane = tid & 63;
    int quad = lane >> 4, lm = lane & 15;
    int wm = (wave >> 2) * 64;
    int wn = (wave & 3) * 64;

    int gx = gridDim.x;
    int bid = blockIdx.y * gx + blockIdx.x;
    int nwg = gx * gridDim.y;
    int cpx = nwg >> 3;
    int swz = (bid & 7) * cpx + (bid >> 3);
    int m0 = (swz / gx) * 128, n0 = (swz % gx) * 256;

    floatx4 acc[4][4];
    #pragma unroll
    for(int i=0;i<4;i++)
        #pragma unroll
        for(int j=0;j<4;j++) acc[i][j] = (floatx4){0.f,0.f,0.f,0.f};

    int srow = tid >> 3;
    int scol = ((tid & 7) ^ (srow & 7)) * 8;
    const u16* aP[2];
    const u16* bP[4];
    #pragma unroll
    for(int p=0;p<2;p++) aP[p] = A  + (size_t)(m0 + p*64 + srow) * K + scol;
    #pragma unroll
    for(int p=0;p<4;p++) bP[p] = Bt + (size_t)(n0 + p*64 + srow) * K + scol;

    int nt = K / 64;
    #pragma unroll
    for(int p=0;p<4;p++) gload16(bP[p], Bs + p*4096 + tid*8);

    for(int t=0; t<nt; ++t){
        int cur = t & 1, nxt = cur ^ 1;
        size_t k0 = (size_t)t * 64;
        #pragma unroll
        for(int p=0;p<2;p++) gload16(aP[p] + k0, As + p*4096 + tid*8);
        if(t+1 < nt){
            #pragma unroll
            for(int p=0;p<4;p++) gload16(bP[p] + k0 + 64, Bs + nxt*16384 + p*4096 + tid*8);
            asm volatile("s_waitcnt vmcnt(4)" ::: "memory");   // retire B(t)+A(t), keep B(t+1) in flight
        } else {
            asm volatile("s_waitcnt vmcnt(0)" ::: "memory");
        }
        __builtin_amdgcn_s_barrier();
        const u16* Bc = Bs + cur*16384;
        #pragma unroll
        for(int ks=0;ks<2;ks++){
            int slotoff = (((ks*4+quad) ^ (lm&7)) << 3);
            bf16x8 af[4], bfr[4];
            #pragma unroll
            for(int i=0;i<4;i++)
                af[i]  = *(const bf16x8*)(As + (wm + i*16 + lm)*64 + slotoff);
            #pragma unroll
            for(int i=0;i<4;i++)
                bfr[i] = *(const bf16x8*)(Bc + (wn + i*16 + lm)*64 + slotoff);
            #pragma unroll
            for(int mf=0;mf<4;mf++)
                #pragma unroll
                for(int nf=0;nf<4;nf++)
                    acc[mf][nf] = __builtin_amdgcn_mfma_f32_16x16x32_bf16(af[mf], bfr[nf], acc[mf][nf], 0, 0, 0);
        }
        __builtin_amdgcn_s_barrier();
    }

    if(EPI == 3 && n0 >= 1536){
        #pragma unroll
        for(int nf=0;nf<4;nf++){
            int col = n0 + wn + nf*16 + lm;
            int hh = (col - 1536) >> 6;
            int d  = col & 63;
            #pragma unroll
            for(int mf=0;mf<4;mf++){
                int row0 = m0 + wm + mf*16 + quad*4;
                int bb  = row0 >> 10;
                int key = row0 & 1023;
                u16x4 pk;
                #pragma unroll
                for(int r=0;r<4;r++) pk[r] = f2bf(acc[mf][nf][r]);
                *(u16x4*)(vt + ((size_t)(bb*HEADS+hh)*64 + d)*SEQ + key) = pk;
            }
        }
        return;
    }

    float bvv[4];
    #pragma unroll
    for(int nf=0;nf<4;nf++) bvv[nf] = bias ? bias[n0 + wn + nf*16 + lm] : 0.f;
    #pragma unroll
    for(int mf=0;mf<4;mf++){
        int row0 = m0 + wm + mf*16 + quad*4;
        #pragma unroll
        for(int r=0;r<4;r++){
            size_t rowoff = (size_t)(row0 + r) * ldc;
            #pragma unroll
            for(int nf=0;nf<4;nf++){              // nf innermost: row's line fills contiguously
                int col = n0 + wn + nf*16 + lm;
                float v = acc[mf][nf][r] + bvv[nf];
                if(EPI == 1) v = gelu_fast(v);
                if(EPI == 3 && col < 768) v *= 0.18033688011112186f;  // Q prescale: 0.125*log2(e)
                ((u16*)Cout)[rowoff + col] = f2bf(v);
            }
        }
    }
}

// ---------------- GEMM narrow: 64x128, BK=64, FULL double-buffer + counted vmcnt(6) -----
// Upgrade of round-8 gemm_bt: BOTH operands double-buffered. LDS 48KB -> 3 blocks/CU.
// Ledger (6 loads/thread/iter): iter t issues tile t+1's 6; vmcnt(6) retires exactly
// tile t's 6 (issued a FULL iteration earlier -> A latency covered too, unlike round-8).
// No prologue drain: first in-loop vmcnt(6) covers tile 0. Proven BK=64 swizzle.
// EPI 2: bias + fp32 residual -> fp32 (proj, fc2).
template<int EPI>
__global__ __launch_bounds__(256,4) void gemm_nar(const u16* __restrict__ A, const u16* __restrict__ Bt,
        void* __restrict__ Cout, const float* __restrict__ bias, const float* __restrict__ res,
        u16* __restrict__ vt, int M, int N, int K, int ldc){
    constexpr int ASZ = 64*64;                   // u16 per A buffer (8 KB)
    constexpr int BSZ = 128*64;                  // u16 per B buffer (16 KB)
    __shared__ __align__(16) u16 As[2*ASZ];
    __shared__ __align__(16) u16 Bs[2*BSZ];
    int tid  = threadIdx.x;
    int wave = tid >> 6, lane = tid & 63;
    int quad = lane >> 4, lm = lane & 15;

    int gx = gridDim.x;
    int bid = blockIdx.y * gx + blockIdx.x;
    int nwg = gx * gridDim.y;
    int cpx = nwg >> 3;
    int swz = (bid & 7) * cpx + (bid >> 3);
    int m0 = (swz / gx) * 64, n0 = (swz % gx) * 128;

    int wm = (wave & 1) * 32;
    int wn = (wave >> 1) * 64;

    floatx4 acc[2][4];
    #pragma unroll
    for(int i=0;i<2;i++)
        #pragma unroll
        for(int j=0;j<4;j++) acc[i][j] = (floatx4){0.f,0.f,0.f,0.f};

    int srow = tid >> 3;
    int scol = ((tid & 7) ^ (srow & 7)) * 8;
    const u16* aP[2];
    const u16* bP[4];
    #pragma unroll
    for(int p=0;p<2;p++) aP[p] = A  + (size_t)(m0 + p*32 + srow) * K + scol;
    #pragma unroll
    for(int p=0;p<4;p++)  bP[p] = Bt + (size_t)(n0 + p*32 + srow) * K + scol;

    int nt = K / 64;
    // prologue: tile 0 into buf 0 (6 loads; retired by iter 0's vmcnt(6))
    #pragma unroll
    for(int p=0;p<2;p++) gload16(aP[p], As + p*2048 + tid*8);
    #pragma unroll
    for(int p=0;p<4;p++) gload16(bP[p], Bs + p*2048 + tid*8);

    for(int t=0; t<nt; ++t){
        int cur = t & 1, nxt = cur ^ 1;
        if(t+1 < nt){
            size_t ko = (size_t)(t+1) * 64;
            #pragma unroll
            for(int p=0;p<2;p++) gload16(aP[p] + ko, As + nxt*ASZ + p*2048 + tid*8);
            #pragma unroll
            for(int p=0;p<4;p++) gload16(bP[p] + ko, Bs + nxt*BSZ + p*2048 + tid*8);
            asm volatile("s_waitcnt vmcnt(6)" ::: "memory");   // retire tile t's 6 (full-iter cover)
        } else {
            asm volatile("s_waitcnt vmcnt(0)" ::: "memory");
        }
        __builtin_amdgcn_s_barrier();
        const u16* Ac = As + cur*ASZ;
        const u16* Bc = Bs + cur*BSZ;
        #pragma unroll
        for(int ks=0;ks<2;ks++){
            int slotoff = (((ks*4+quad) ^ (lm&7)) << 3);
            bf16x8 af[2], bfr[4];
            #pragma unroll
            for(int i=0;i<2;i++)
                af[i]  = *(const bf16x8*)(Ac + (wm + i*16 + lm)*64 + slotoff);
            #pragma unroll
            for(int i=0;i<4;i++)
                bfr[i] = *(const bf16x8*)(Bc + (wn + i*16 + lm)*64 + slotoff);
            #pragma unroll
            for(int mf=0;mf<2;mf++)
                #pragma unroll
                for(int nf=0;nf<4;nf++)
                    acc[mf][nf] = __builtin_amdgcn_mfma_f32_16x16x32_bf16(af[mf], bfr[nf], acc[mf][nf], 0, 0, 0);
        }
        __builtin_amdgcn_s_barrier();
    }

    float bvv[4];
    #pragma unroll
    for(int nf=0;nf<4;nf++) bvv[nf] = bias ? bias[n0 + wn + nf*16 + lm] : 0.f;
    #pragma unroll
    for(int mf=0;mf<2;mf++){
        int row0 = m0 + wm + mf*16 + quad*4;
        #pragma unroll
        for(int r=0;r<4;r++){
            size_t rowoff = (size_t)(row0 + r) * ldc;
            #pragma unroll
            for(int nf=0;nf<4;nf++){              // nf innermost
                int col = n0 + wn + nf*16 + lm;
                float v = acc[mf][nf][r] + bvv[nf];
                if(EPI == 2){
                    ((float*)Cout)[rowoff + col] = v + res[rowoff + col];
                } else {
                    ((u16*)Cout)[rowoff + col] = f2bf(v);
                }
            }
        }
    }
}

// ---------------- flash attention: S^T formulation, VALU-lean softmax ----------------
__global__ __launch_bounds__(256) void attn_kernel(const u16* __restrict__ qk, const u16* __restrict__ vt,
                                                   u16* __restrict__ out){
    int bid = blockIdx.x;
    int hb = bid % 96;
    int qt = bid / 96;
    int h = hb % HEADS, b = hb / HEADS;
    int tid = threadIdx.x;
    int wave = tid >> 6, lane = tid & 63;
    int quad = lane >> 4, lm = lane & 15;

    __shared__ __align__(16) u16 Ks[2*64*64];
    __shared__ __align__(16) u16 Vs[2*64*64];
    __shared__ __align__(16) u16 P[4*32*64];

    const u16* qbase = qk + (size_t)b * SEQ * 1536;
    const u16* vbase = vt + (size_t)(b*HEADS + h) * 64 * SEQ;
    u16* Pw = P + wave*2048;

    int q0 = qt*128 + wave*32;
    bf16x8 qf[2][2];
    #pragma unroll
    for(int qi=0;qi<2;qi++){
        const u16* qp = qbase + (size_t)(q0 + qi*16 + lm)*1536 + h*64;
        qf[qi][0] = *(const bf16x8*)(qp + quad*8);
        qf[qi][1] = *(const bf16x8*)(qp + 32 + quad*8);
    }

    float l_i[2] = {0.f, 0.f};
    floatx4 o_acc[2][4];
    #pragma unroll
    for(int qi=0;qi<2;qi++)
        #pragma unroll
        for(int nf=0;nf<4;nf++) o_acc[qi][nf] = (floatx4){0.f,0.f,0.f,0.f};

    int sr = lane >> 3;
    int sp = lane & 7;

    auto stage = [&](int kt, int buf){
        #pragma unroll
        for(int i=0;i<2;i++){
            int rr = wave*16 + i*8 + sr;
            int sw = (sp ^ (rr & 7)) * 8;
            gload16(qbase + (size_t)(kt*64 + rr)*1536 + 768 + h*64 + sw,
                    Ks + buf*4096 + (wave*16 + i*8)*64 + lane*8);
            gload16(vbase + (size_t)rr*SEQ + kt*64 + sw,
                    Vs + buf*4096 + (wave*16 + i*8)*64 + lane*8);
        }
    };

    stage(0, 0);
    __syncthreads();

    int cur = 0;
    for(int kt=0; kt<16; kt++){
        if(kt < 15) stage(kt+1, cur^1);
        const u16* Ksb = Ks + cur*4096;
        const u16* Vsb = Vs + cur*4096;

        floatx4 s[4][2];
        #pragma unroll
        for(int kf=0;kf<4;kf++){
            int krow = kf*16 + lm;
            bf16x8 k0 = *(const bf16x8*)(Ksb + krow*64 + ((quad     ^ (lm&7))*8));
            bf16x8 k1 = *(const bf16x8*)(Ksb + krow*64 + (((4+quad) ^ (lm&7))*8));
            #pragma unroll
            for(int qi=0;qi<2;qi++){
                floatx4 t = (floatx4){0.f,0.f,0.f,0.f};
                t = __builtin_amdgcn_mfma_f32_16x16x32_bf16(k0, qf[qi][0], t, 0, 0, 0);
                t = __builtin_amdgcn_mfma_f32_16x16x32_bf16(k1, qf[qi][1], t, 0, 0, 0);
                s[kf][qi] = t;
            }
        }

        #pragma unroll
        for(int qi=0;qi<2;qi++){
            float part = 0.f;
            #pragma unroll
            for(int kf=0;kf<4;kf++){
                #pragma unroll
                for(int r=0;r<4;r++){
                    float e = exp2f(s[kf][qi][r]);     // Q prescaled: no *C
                    s[kf][qi][r] = e;
                    part += e;
                }
            }
            l_i[qi] += part;
            #pragma unroll
            for(int kf=0;kf<4;kf++){
                uint2 pk2;
                pk2.x = cvt_pk_bf16(s[kf][qi][0], s[kf][qi][1]);
                pk2.y = cvt_pk_bf16(s[kf][qi][2], s[kf][qi][3]);
                int c  = kf*4 + quad;
                int cp = c ^ (2*(lm & 7));
                *(uint2*)(Pw + (qi*16 + lm)*64 + cp*4) = pk2;
            }
        }

        #pragma unroll
        for(int ks=0;ks<2;ks++){
            bf16x8 vf[4];
            #pragma unroll
            for(int nf=0;nf<4;nf++)
                vf[nf] = *(const bf16x8*)(Vsb + (nf*16+lm)*64 + (((ks*4+quad) ^ (lm&7))*8));
            #pragma unroll
            for(int qi=0;qi<2;qi++){
                int cr = (ks*8 + 2*quad) ^ (2*(lm & 7));
                bf16x8 pa = *(const bf16x8*)(Pw + (qi*16 + lm)*64 + cr*4);
                #pragma unroll
                for(int nf=0;nf<4;nf++)
                    o_acc[qi][nf] = __builtin_amdgcn_mfma_f32_16x16x32_bf16(pa, vf[nf], o_acc[qi][nf], 0, 0, 0);
            }
        }
        if(kt < 15) __syncthreads();
        cur ^= 1;
    }

    #pragma unroll
    for(int qi=0;qi<2;qi++){
        float lf = l_i[qi];
        lf += __shfl_xor(lf, 16);
        lf += __shfl_xor(lf, 32);
        float rl[4];
        #pragma unroll
        for(int r=0;r<4;r++) rl[r] = 1.0f / __shfl(lf, quad*4 + r);
        int token = b*SEQ + qt*128 + wave*32 + qi*16 + quad*4;
        #pragma unroll
        for(int r=0;r<4;r++){
            size_t rowoff = (size_t)(token + r)*EMBED + h*64;
            #pragma unroll
            for(int nf=0;nf<4;nf++){
                out[rowoff + nf*16 + lm] = f2bf(o_acc[qi][nf][r] * rl[r]);
            }
        }
    }
}

extern "C" void kernel_launch(void* const* d_in, const int* in_sizes, int n_in,
                              void* d_out, int out_size, void* d_ws, size_t ws_size,
                              hipStream_t stream) {
    const float* x      = (const float*)d_in[0];
    const float* g1     = (const float*)d_in[1];
    const float* b1     = (const float*)d_in[2];
    const float* g2     = (const float*)d_in[3];
    const float* b2     = (const float*)d_in[4];
    const float* w_qkv  = (const float*)d_in[5];
    const float* w_proj = (const float*)d_in[6];
    const float* b_proj = (const float*)d_in[7];
    const float* w_fc1  = (const float*)d_in[8];
    const float* b_fc1  = (const float*)d_in[9];
    const float* w_fc2  = (const float*)d_in[10];
    const float* b_fc2  = (const float*)d_in[11];
    float* out = (float*)d_out;

    char* ws = (char*)d_ws;
    u16*   wqkv_t  = (u16*)  (ws + 0);
    u16*   wproj_t = (u16*)  (ws + 3538944);
    u16*   wfc1_t  = (u16*)  (ws + 4718592);
    u16*   wfc2_t  = (u16*)  (ws + 9437184);
    float* x1      = (float*)(ws + 14155776);
    u16*   hbuf    = (u16*)  (ws + 39321600);
    u16*   qkbuf   = (u16*)  (ws + 51904512);
    u16*   vtbuf   = (u16*)  (ws + 77070336);
    u16*   attn_o  = (u16*)  (ws + 89653248);
    u16*   fc1_o   = qkbuf;
    u16*   h2      = hbuf;

    prep_kernel<<<8960, 256, 0, stream>>>(w_qkv, w_proj, w_fc1, w_fc2,
                                          wqkv_t, wproj_t, wfc1_t, wfc2_t,
                                          x, g1, b1, hbuf);

    gemm_wide<3><<<dim3(2304/256, TOKENS/128), 512, 0, stream>>>(hbuf, wqkv_t, qkbuf, nullptr, nullptr, vtbuf, TOKENS, 2304, 768, 1536);

    attn_kernel<<<768, 256, 0, stream>>>(qkbuf, vtbuf, attn_o);

    gemm_nar<2><<<dim3( 768/128, TOKENS/64), 256, 0, stream>>>(attn_o, wproj_t, x1, b_proj, x, nullptr, TOKENS, 768, 768, 768);

    ln_kernel<<<TOKENS/4, 256, 0, stream>>>(x1, g2, b2, h2);

    gemm_wide<1><<<dim3(3072/256, TOKENS/128), 512, 0, stream>>>(h2, wfc1_t, fc1_o, b_fc1, nullptr, nullptr, TOKENS, 3072, 768, 3072);

    gemm_nar<2><<<dim3( 768/128, TOKENS/64), 256, 0, stream>>>(fc1_o, wfc2_t, out, b_fc2, x1, nullptr, TOKENS, 768, 3072, 768);
}